// Round 3
// baseline (63.199 us; speedup 1.0000x reference)
//
#include <hip/hip_runtime.h>
#include <hip/hip_bf16.h>
#include <math.h>

#define NCONF  256
#define NATOMS 128
#define NATOT  (NCONF * NATOMS)
#define PER_ATOM 1216   // 9*64 + 4*64 + 6*64

__global__ __launch_bounds__(256) void OrbitalAEVComputer_38895223833089_kernel(
    const float* __restrict__ coeff,     // (NATOT, 21) f32
    const float* __restrict__ nlib,      // (4, 7, 9) f32
    const int*   __restrict__ sp32,      // species, int32 OR int64 (detected)
    float* __restrict__ out)             // (NATOT, 1216) f32
{
    __shared__ float s_chan[13];          // 9 s-centers + 4 p-norm centers
    __shared__ float s_ca[6], s_sa[6];    // cos/sin of the 6 pair angles
    __shared__ float s_ct[64], s_st[64];  // cos/sin of shfT grid

    const int atom = blockIdx.x;
    const int tid  = threadIdx.x;

    if (tid < 64) {
        float t = (float)tid * (float)(M_PI / 63.0);
        s_ct[tid] = cosf(t);
        s_st[tid] = sinf(t);
    }

    if (tid == 0) {
        const float* c = coeff + (size_t)atom * 21;
        // species dtype runtime detection:
        //   int64 (jax x64): little-endian, sp32[1] is the high word of
        //   species[0] == 0 (Z values are tiny). int32: sp32[1] is
        //   species[1] in {1,6,7,8,9,16,17}, never 0.
        const int is64 = (sp32[1] == 0);
        const int z = is64 ? sp32[(size_t)atom * 2] : sp32[atom];
        int sidx;
        switch (z) {
            case 1:  sidx = 0; break;
            case 6:  sidx = 1; break;
            case 7:  sidx = 2; break;
            case 8:  sidx = 3; break;
            case 9:  sidx = 4; break;
            case 16: sidx = 5; break;
            default: sidx = 6; break;   // 17
        }
        const float* s_mus = nlib + 0 * 63 + sidx * 9;
        const float* s_sig = nlib + 1 * 63 + sidx * 9;
        const float* p_mus = nlib + 2 * 63 + sidx * 9;
        const float* p_sig = nlib + 3 * 63 + sidx * 9;

        #pragma unroll
        for (int k = 0; k < 9; ++k)
            s_chan[k] = (c[k] - s_mus[k]) / s_sig[k];

        float M[4][3];
        #pragma unroll
        for (int i = 0; i < 4; ++i) {
            M[i][0] = c[9 + i * 3 + 0];
            M[i][1] = c[9 + i * 3 + 1];
            M[i][2] = c[9 + i * 3 + 2];
            float nn = M[i][0]*M[i][0] + M[i][1]*M[i][1] + M[i][2]*M[i][2];
            float nrm = sqrtf(nn);
            bool zero = (fabsf(M[i][0]) < 1e-12f) &&
                        (fabsf(M[i][1]) < 1e-12f) &&
                        (fabsf(M[i][2]) < 1e-12f);
            s_chan[9 + i] = (nrm - p_mus[i]) / p_sig[i];
            float inv = zero ? 0.0f : (1.0f / nrm);
            M[i][0] *= inv; M[i][1] *= inv; M[i][2] *= inv;
        }
        const int iu[6] = {0, 0, 0, 1, 1, 2};
        const int ju[6] = {1, 2, 3, 2, 3, 3};
        #pragma unroll
        for (int p = 0; p < 6; ++p) {
            int i = iu[p], j = ju[p];
            float d = M[i][0]*M[j][0] + M[i][1]*M[j][1] + M[i][2]*M[j][2];
            d = fminf(fmaxf(d, -0.9999f), 0.9999f);
            s_ca[p] = d;
            s_sa[p] = sqrtf(fmaxf(1.0f - d * d, 0.0f));
        }
    }
    __syncthreads();

    float* po = out + (size_t)atom * PER_ATOM;
    const float K = 11.541560327111707f;  // 8 * log2(e)

    // 1216 outputs = 304 quads of 4 consecutive shf bins (16B coalesced stores)
    for (int q = tid; q < 304; q += 256) {
        const int ch = q >> 4;          // channel 0..18
        const int j0 = (q & 15) << 2;   // shf bin base 0..60
        float4 v;
        float vv[4];
        if (ch < 13) {
            // exp(-8 (x - shf)^2) = exp2(-K d^2)
            float x = s_chan[ch];
            #pragma unroll
            for (int jj = 0; jj < 4; ++jj) {
                float shf = -3.0f + (float)(j0 + jj) * (6.0f / 63.0f);
                float d = x - shf;
                vv[jj] = exp2f(-K * d * d);
            }
        } else {
            // 2^-7 * ((1 + cos(angle - shfT)) / 2)^8,
            // cos(angle - t) = ca*cos(t) + sa*sin(t), sin(angle) = sa >= 0
            int p = ch - 13;
            float cap = s_ca[p], sap = s_sa[p];
            #pragma unroll
            for (int jj = 0; jj < 4; ++jj) {
                float t  = 0.5f + 0.5f * (cap * s_ct[j0 + jj] + sap * s_st[j0 + jj]);
                float t2 = t * t;
                float t4 = t2 * t2;
                vv[jj] = 0.0078125f * (t4 * t4);
            }
        }
        v.x = vv[0]; v.y = vv[1]; v.z = vv[2]; v.w = vv[3];
        *reinterpret_cast<float4*>(po + q * 4) = v;
    }
}

extern "C" void kernel_launch(void* const* d_in, const int* in_sizes, int n_in,
                              void* d_out, int out_size, void* d_ws, size_t ws_size,
                              hipStream_t stream) {
    const float* coeff   = (const float*)d_in[0];
    const float* nlib    = (const float*)d_in[1];
    const int*   sp32    = (const int*)d_in[2];
    float* out           = (float*)d_out;

    OrbitalAEVComputer_38895223833089_kernel<<<dim3(NATOT), dim3(256), 0, stream>>>(
        coeff, nlib, sp32, out);
}

// Round 4
// 38.978 us; speedup vs baseline: 1.6214x; 1.6214x over previous
//
#include <hip/hip_runtime.h>
#include <hip/hip_bf16.h>
#include <math.h>

#define NCONF  256
#define NATOMS 128
#define NATOT  (NCONF * NATOMS)
#define PER_ATOM 1216        // 9*64 + 4*64 + 6*64
#define NQUAD  304           // PER_ATOM / 4
#define TOTQ   (NATOT * NQUAD)
#define PSTR   25            // 13 chan + 6 ca + 6 sa
#define WS_FLOATS (128 + NATOT * PSTR)

__device__ __forceinline__ int species_to_sidx(int z) {
    switch (z) {
        case 1:  return 0;
        case 6:  return 1;
        case 7:  return 2;
        case 8:  return 3;
        case 9:  return 4;
        case 16: return 5;
        default: return 6;   // 17
    }
}

// ---------------- Kernel P: per-atom params (one thread per atom) ----------
__global__ __launch_bounds__(256) void aev_params_kernel(
    const float* __restrict__ coeff,   // (NATOT, 21)
    const float* __restrict__ nlib,    // (4, 7, 9)
    const int*   __restrict__ sp32,    // int32 or int64 (runtime-detected)
    float* __restrict__ ws)            // [0..127] cos/sin table, then params
{
    const int tid  = threadIdx.x;
    const int atom = blockIdx.x * blockDim.x + tid;

    if (blockIdx.x == 0 && tid < 64) {
        float t = (float)tid * (float)(M_PI / 63.0);
        ws[tid]      = cosf(t);
        ws[64 + tid] = sinf(t);
    }
    if (atom >= NATOT) return;

    // species dtype runtime detection: int64 => sp32[1] is high word of
    // species[0] == 0; int32 => sp32[1] in {1,6,7,8,9,16,17} != 0.
    const int is64 = (sp32[1] == 0);
    const int z = is64 ? sp32[(size_t)atom * 2] : sp32[atom];
    const int sidx = species_to_sidx(z);

    const float* c     = coeff + (size_t)atom * 21;
    const float* s_mus = nlib + 0 * 63 + sidx * 9;
    const float* s_sig = nlib + 1 * 63 + sidx * 9;
    const float* p_mus = nlib + 2 * 63 + sidx * 9;
    const float* p_sig = nlib + 3 * 63 + sidx * 9;

    float* P = ws + 128 + (size_t)atom * PSTR;

    #pragma unroll
    for (int k = 0; k < 9; ++k)
        P[k] = (c[k] - s_mus[k]) / s_sig[k];

    float M[4][3];
    #pragma unroll
    for (int i = 0; i < 4; ++i) {
        M[i][0] = c[9 + i * 3 + 0];
        M[i][1] = c[9 + i * 3 + 1];
        M[i][2] = c[9 + i * 3 + 2];
        float nn  = M[i][0]*M[i][0] + M[i][1]*M[i][1] + M[i][2]*M[i][2];
        float nrm = sqrtf(nn);
        bool zero = (fabsf(M[i][0]) < 1e-12f) &&
                    (fabsf(M[i][1]) < 1e-12f) &&
                    (fabsf(M[i][2]) < 1e-12f);
        P[9 + i] = (nrm - p_mus[i]) / p_sig[i];
        float inv = zero ? 0.0f : (1.0f / nrm);
        M[i][0] *= inv; M[i][1] *= inv; M[i][2] *= inv;
    }
    const int iu[6] = {0, 0, 0, 1, 1, 2};
    const int ju[6] = {1, 2, 3, 2, 3, 3};
    #pragma unroll
    for (int p = 0; p < 6; ++p) {
        int i = iu[p], j = ju[p];
        float d = M[i][0]*M[j][0] + M[i][1]*M[j][1] + M[i][2]*M[j][2];
        d = fminf(fmaxf(d, -0.9999f), 0.9999f);
        P[13 + p] = d;
        P[19 + p] = sqrtf(fmaxf(1.0f - d * d, 0.0f));
    }
}

// ---------------- Kernel S: pure streaming (one thread per output quad) ----
__global__ __launch_bounds__(256) void aev_stream_kernel(
    const float* __restrict__ ws,
    float* __restrict__ out)
{
    const int g = blockIdx.x * 256 + threadIdx.x;
    if (g >= TOTQ) return;                 // TOTQ % 256 == 0: never taken
    const int atom = g / NQUAD;            // magic-mul division
    const int q    = g - atom * NQUAD;
    const int ch   = q >> 4;               // channel 0..18
    const int j0   = (q & 15) << 2;        // shf bin base 0..60

    const float* P = ws + 128 + (size_t)atom * PSTR;
    const float K = 11.541560327111707f;   // 8 * log2(e)

    float vv[4];
    if (ch < 13) {
        float x = P[ch];
        #pragma unroll
        for (int jj = 0; jj < 4; ++jj) {
            float shf = -3.0f + (float)(j0 + jj) * (6.0f / 63.0f);
            float d = x - shf;
            vv[jj] = exp2f(-K * d * d);
        }
    } else {
        int p = ch - 13;
        float cap = P[13 + p], sap = P[19 + p];
        float4 ct = *reinterpret_cast<const float4*>(ws + j0);       // 16B-aligned
        float4 st = *reinterpret_cast<const float4*>(ws + 64 + j0);
        float cts[4] = {ct.x, ct.y, ct.z, ct.w};
        float sts[4] = {st.x, st.y, st.z, st.w};
        #pragma unroll
        for (int jj = 0; jj < 4; ++jj) {
            float t  = 0.5f + 0.5f * (cap * cts[jj] + sap * sts[jj]);
            float t2 = t * t;
            float t4 = t2 * t2;
            vv[jj] = 0.0078125f * (t4 * t4);
        }
    }
    float4 v; v.x = vv[0]; v.y = vv[1]; v.z = vv[2]; v.w = vv[3];
    *reinterpret_cast<float4*>(out + (size_t)atom * PER_ATOM + q * 4) = v;
}

// ---------------- Fallback: proven round-3 monolithic kernel ---------------
__global__ __launch_bounds__(256) void aev_mono_kernel(
    const float* __restrict__ coeff,
    const float* __restrict__ nlib,
    const int*   __restrict__ sp32,
    float* __restrict__ out)
{
    __shared__ float s_chan[13];
    __shared__ float s_ca[6], s_sa[6];
    __shared__ float s_ct[64], s_st[64];

    const int atom = blockIdx.x;
    const int tid  = threadIdx.x;

    if (tid < 64) {
        float t = (float)tid * (float)(M_PI / 63.0);
        s_ct[tid] = cosf(t);
        s_st[tid] = sinf(t);
    }
    if (tid == 0) {
        const float* c = coeff + (size_t)atom * 21;
        const int is64 = (sp32[1] == 0);
        const int z = is64 ? sp32[(size_t)atom * 2] : sp32[atom];
        const int sidx = species_to_sidx(z);
        const float* s_mus = nlib + 0 * 63 + sidx * 9;
        const float* s_sig = nlib + 1 * 63 + sidx * 9;
        const float* p_mus = nlib + 2 * 63 + sidx * 9;
        const float* p_sig = nlib + 3 * 63 + sidx * 9;
        #pragma unroll
        for (int k = 0; k < 9; ++k)
            s_chan[k] = (c[k] - s_mus[k]) / s_sig[k];
        float M[4][3];
        #pragma unroll
        for (int i = 0; i < 4; ++i) {
            M[i][0] = c[9+i*3+0]; M[i][1] = c[9+i*3+1]; M[i][2] = c[9+i*3+2];
            float nn  = M[i][0]*M[i][0] + M[i][1]*M[i][1] + M[i][2]*M[i][2];
            float nrm = sqrtf(nn);
            bool zero = (fabsf(M[i][0]) < 1e-12f) && (fabsf(M[i][1]) < 1e-12f) &&
                        (fabsf(M[i][2]) < 1e-12f);
            s_chan[9+i] = (nrm - p_mus[i]) / p_sig[i];
            float inv = zero ? 0.0f : (1.0f / nrm);
            M[i][0] *= inv; M[i][1] *= inv; M[i][2] *= inv;
        }
        const int iu[6] = {0,0,0,1,1,2};
        const int ju[6] = {1,2,3,2,3,3};
        #pragma unroll
        for (int p = 0; p < 6; ++p) {
            int i = iu[p], j = ju[p];
            float d = M[i][0]*M[j][0] + M[i][1]*M[j][1] + M[i][2]*M[j][2];
            d = fminf(fmaxf(d, -0.9999f), 0.9999f);
            s_ca[p] = d;
            s_sa[p] = sqrtf(fmaxf(1.0f - d*d, 0.0f));
        }
    }
    __syncthreads();

    float* po = out + (size_t)atom * PER_ATOM;
    const float K = 11.541560327111707f;
    for (int q = tid; q < NQUAD; q += 256) {
        const int ch = q >> 4;
        const int j0 = (q & 15) << 2;
        float vv[4];
        if (ch < 13) {
            float x = s_chan[ch];
            #pragma unroll
            for (int jj = 0; jj < 4; ++jj) {
                float shf = -3.0f + (float)(j0 + jj) * (6.0f / 63.0f);
                float d = x - shf;
                vv[jj] = exp2f(-K * d * d);
            }
        } else {
            int p = ch - 13;
            float cap = s_ca[p], sap = s_sa[p];
            #pragma unroll
            for (int jj = 0; jj < 4; ++jj) {
                float t  = 0.5f + 0.5f * (cap * s_ct[j0+jj] + sap * s_st[j0+jj]);
                float t2 = t * t;
                float t4 = t2 * t2;
                vv[jj] = 0.0078125f * (t4 * t4);
            }
        }
        float4 v; v.x = vv[0]; v.y = vv[1]; v.z = vv[2]; v.w = vv[3];
        *reinterpret_cast<float4*>(po + q * 4) = v;
    }
}

extern "C" void kernel_launch(void* const* d_in, const int* in_sizes, int n_in,
                              void* d_out, int out_size, void* d_ws, size_t ws_size,
                              hipStream_t stream) {
    const float* coeff   = (const float*)d_in[0];
    const float* nlib    = (const float*)d_in[1];
    const int*   sp32    = (const int*)d_in[2];
    float* out           = (float*)d_out;
    float* ws            = (float*)d_ws;

    if (ws_size >= (size_t)WS_FLOATS * sizeof(float)) {
        aev_params_kernel<<<dim3((NATOT + 255) / 256), dim3(256), 0, stream>>>(
            coeff, nlib, sp32, ws);
        aev_stream_kernel<<<dim3(TOTQ / 256), dim3(256), 0, stream>>>(ws, out);
    } else {
        aev_mono_kernel<<<dim3(NATOT), dim3(256), 0, stream>>>(
            coeff, nlib, sp32, out);
    }
}